// Round 6
// baseline (210.900 us; speedup 1.0000x reference)
//
#include <hip/hip_runtime.h>
#include <stdint.h>

typedef unsigned short u16;
typedef unsigned int   u32;
typedef short short8 __attribute__((ext_vector_type(8)));
typedef float f32x4  __attribute__((ext_vector_type(4)));

// ---------- helpers ----------
__device__ __forceinline__ u16 f2bf(float f){
  u32 u = __builtin_bit_cast(u32, f);
  u32 r = (u + 0x7FFFu + ((u >> 16) & 1u)) >> 16;   // RNE
  return (u16)r;
}
__device__ __forceinline__ u32 cvtpk(float a, float b){   // lo=bf16(a), hi=bf16(b), RNE
  u32 r; asm("v_cvt_pk_bf16_f32 %0, %1, %2" : "=v"(r) : "v"(a), "v"(b)); return r;
}
// async global->LDS, 16B per lane. LDS dest = wave-uniform base + lane*16.
__device__ __forceinline__ void gload16(const u16* g, u16* l){
  __builtin_amdgcn_global_load_lds((const __attribute__((address_space(1))) void*)g,
                                   (__attribute__((address_space(3))) void*)l, 16, 0, 0);
}

// ---------- x f32 -> bf16 ----------
__global__ __launch_bounds__(256) void k_cvt_bf16(const float* __restrict__ x,
                                                  u16* __restrict__ y, int n8){
  int i = blockIdx.x * 256 + threadIdx.x;
  if (i >= n8) return;
  const float4* p = (const float4*)x + (size_t)i * 2;
  float4 a = p[0], b = p[1];
  short8 o;
  o[0] = f2bf(a.x); o[1] = f2bf(a.y); o[2] = f2bf(a.z); o[3] = f2bf(a.w);
  o[4] = f2bf(b.x); o[5] = f2bf(b.y); o[6] = f2bf(b.z); o[7] = f2bf(b.w);
  *(short8*)(y + (size_t)i * 8) = o;
}

// ---------- weight transpose: in f32[R][C] -> out bf16[C][R] ----------
__global__ __launch_bounds__(256) void k_transpose_w(const float* __restrict__ in,
                                                     u16* __restrict__ out, int R, int C){
  __shared__ float tile[32][33];
  int nc = C >> 5;
  int cb = blockIdx.x % nc, rb = blockIdx.x / nc;
  int tx = threadIdx.x & 31, ty = threadIdx.x >> 5;
#pragma unroll
  for (int i = 0; i < 4; ++i){
    int r = rb * 32 + ty + i * 8;
    tile[ty + i * 8][tx] = in[(size_t)r * C + cb * 32 + tx];
  }
  __syncthreads();
#pragma unroll
  for (int i = 0; i < 4; ++i){
    int c = cb * 32 + ty + i * 8;
    out[(size_t)c * R + rb * 32 + tx] = f2bf(tile[tx][ty + i * 8]);
  }
}

// ---------- QKV GEMM: c1[4096][3072] = A[4096][2048] * Bt[3072][2048]^T ----------
// BM=256, BN=192, BK=64, 8 waves (2m x 4n), 2 LDS buffers, 4 phases/K-tile,
// reads one phase ahead, XOR-swizzled LDS, setprio, Q-columns pre-scaled by log2(e)/8.
template<int BN, int NFRAG, int BLOADS, bool QSCALE, typename CT>
__global__ __launch_bounds__(512, 2) void k_gemm8p(const u16* __restrict__ A,
                                                   const u16* __restrict__ Bt,
                                                   CT* __restrict__ C,
                                                   int N, int K){
  constexpr int SZA = 256 * 128;
  constexpr int SZB = BN * 128;
  constexpr int SZ  = SZA + SZB;
  constexpr int WT_N = BN / 4;
  __shared__ char lds[2 * SZ];

  int tid = threadIdx.x, lane = tid & 63, wid = tid >> 6;
  int l16 = lane & 15, g4 = lane >> 4;
  int wm = wid >> 2, wn = wid & 3;
  int bid = blockIdx.x;
  int wg = (bid & 7) * 32 + (bid >> 3);
  int bm = wg >> 4, bn = wg & 15;

  const u16* baseA = A  + (size_t)(bm * 256) * K;
  const u16* baseB = Bt + (size_t)(bn * BN) * K;

  int aLds[4], aG[4];
#pragma unroll
  for (int i = 0; i < 4; ++i){
    int q = (wid * 4 + i) * 1024 + lane * 16;
    int row = q >> 7, c = q & 127;
    int cs = c ^ ((row & 7) << 4);
    aLds[i] = q; aG[i] = row * K + (cs >> 1);
  }
  int bLds[BLOADS], bG[BLOADS];
#pragma unroll
  for (int j = 0; j < BLOADS; ++j){
    int q = (wid * BLOADS + j) * 1024 + lane * 16;
    int row = q >> 7, c = q & 127;
    int cs = c ^ ((row & 7) << 4);
    bLds[j] = q; bG[j] = row * K + (cs >> 1);
  }
  auto stageA = [&](int t){
    char* dst = lds + (t & 1) * SZ;
#pragma unroll
    for (int i = 0; i < 4; ++i) gload16(baseA + aG[i] + t * 64, (u16*)(dst + aLds[i]));
  };
  auto stageB = [&](int t){
    char* dst = lds + (t & 1) * SZ + SZA;
#pragma unroll
    for (int j = 0; j < BLOADS; ++j) gload16(baseB + bG[j] + t * 64, (u16*)(dst + bLds[j]));
  };
  auto rdA = [&](const char* Ab, int m, int ks){
    int row = wm * 128 + m * 16 + l16;
    return *(const short8*)(Ab + row * 128 + ((ks * 64 + g4 * 16) ^ ((row & 7) << 4)));
  };
  auto rdB = [&](const char* Bb, int nf, int ks){
    int row = wn * WT_N + nf * 16 + l16;
    return *(const short8*)(Bb + row * 128 + ((ks * 64 + g4 * 16) ^ ((row & 7) << 4)));
  };

  f32x4 zero4 = {0.f, 0.f, 0.f, 0.f};
  f32x4 acc[8][NFRAG];
#pragma unroll
  for (int i = 0; i < 8; ++i)
#pragma unroll
    for (int j = 0; j < NFRAG; ++j) acc[i][j] = zero4;

  int NK = K >> 6;
  stageA(0); stageB(0);
  asm volatile("s_waitcnt vmcnt(0)" ::: "memory");

  for (int kt = 0; kt < NK; ++kt){
    const char* Ab = lds + (kt & 1) * SZ;
    const char* Bb = Ab + SZA;
    bool st = (kt + 1 < NK);
    __builtin_amdgcn_s_barrier();
    // phase a
    short8 bf0[NFRAG], a0[4], a1[4], bf1[NFRAG], a2[4], a3[4];
#pragma unroll
    for (int nf = 0; nf < NFRAG; ++nf) bf0[nf] = rdB(Bb, nf, 0);
#pragma unroll
    for (int m = 0; m < 4; ++m) a0[m] = rdA(Ab, m, 0);
    if (st) stageA(kt + 1);
#pragma unroll
    for (int m = 0; m < 4; ++m) a1[m] = rdA(Ab, 4 + m, 0);
    __builtin_amdgcn_s_setprio(1);
#pragma unroll
    for (int m = 0; m < 4; ++m)
#pragma unroll
      for (int nf = 0; nf < NFRAG; ++nf)
        acc[m][nf] = __builtin_amdgcn_mfma_f32_16x16x32_bf16(a0[m], bf0[nf], acc[m][nf], 0, 0, 0);
    __builtin_amdgcn_s_setprio(0);
    __builtin_amdgcn_s_barrier();
    // phase b
    if (st) stageB(kt + 1);
#pragma unroll
    for (int nf = 0; nf < NFRAG; ++nf) bf1[nf] = rdB(Bb, nf, 1);
#pragma unroll
    for (int m = 0; m < 4; ++m) a2[m] = rdA(Ab, m, 1);
    __builtin_amdgcn_s_setprio(1);
#pragma unroll
    for (int m = 0; m < 4; ++m)
#pragma unroll
      for (int nf = 0; nf < NFRAG; ++nf)
        acc[4 + m][nf] = __builtin_amdgcn_mfma_f32_16x16x32_bf16(a1[m], bf0[nf], acc[4 + m][nf], 0, 0, 0);
    __builtin_amdgcn_s_setprio(0);
    __builtin_amdgcn_s_barrier();
    // phase c
#pragma unroll
    for (int m = 0; m < 4; ++m) a3[m] = rdA(Ab, 4 + m, 1);
    __builtin_amdgcn_s_setprio(1);
#pragma unroll
    for (int m = 0; m < 4; ++m)
#pragma unroll
      for (int nf = 0; nf < NFRAG; ++nf)
        acc[m][nf] = __builtin_amdgcn_mfma_f32_16x16x32_bf16(a2[m], bf1[nf], acc[m][nf], 0, 0, 0);
    __builtin_amdgcn_s_setprio(0);
    __builtin_amdgcn_s_barrier();
    // phase d
    __builtin_amdgcn_s_setprio(1);
#pragma unroll
    for (int m = 0; m < 4; ++m)
#pragma unroll
      for (int nf = 0; nf < NFRAG; ++nf)
        acc[4 + m][nf] = __builtin_amdgcn_mfma_f32_16x16x32_bf16(a3[m], bf1[nf], acc[4 + m][nf], 0, 0, 0);
    __builtin_amdgcn_s_setprio(0);
    if (st) asm volatile("s_waitcnt vmcnt(0)" ::: "memory");
  }

#pragma unroll
  for (int mf = 0; mf < 8; ++mf)
#pragma unroll
    for (int nf = 0; nf < NFRAG; ++nf)
#pragma unroll
      for (int r = 0; r < 4; ++r){
        int row = bm * 256 + wm * 128 + mf * 16 + g4 * 4 + r;
        int col = bn * BN + wn * WT_N + nf * 16 + l16;
        float vv = acc[mf][nf][r];
        if constexpr (QSCALE) { if (col < 2048) vv *= 0.18033688011112042f; }  // log2(e)/8
        if constexpr (sizeof(CT) == 2) C[(size_t)row * N + col] = (CT)f2bf(vv);
        else                           C[(size_t)row * N + col] = (CT)vv;
      }
}

// ---------- O-proj GEMM: out[4096][2048] = att[4096][2048] * wot[2048][2048]^T ----------
// BM=128, BN=256, BK=64, 8 waves (2m x 4n) wave-tile 64x64, 3 LDS buffers (144KB),
// 2-K-tile prefetch lead, counted vmcnt(6), ONE barrier per K-tile (T3+T4).
__global__ __launch_bounds__(512, 1) void k_gemm_o(const u16* __restrict__ A,
                                                   const u16* __restrict__ Bt,
                                                   float* __restrict__ C,
                                                   int N, int K){
  constexpr int SZA = 128 * 128;   // 16 KB
  constexpr int SZB = 256 * 128;   // 32 KB
  constexpr int SZ  = SZA + SZB;   // 48 KB
  __shared__ char lds[3 * SZ];     // 144 KB

  int tid = threadIdx.x, lane = tid & 63, wid = tid >> 6;
  int l16 = lane & 15, g4 = lane >> 4;
  int wm = wid >> 2, wn = wid & 3;
  int bid = blockIdx.x;
  int wg = (bid & 7) * 32 + (bid >> 3);     // 256 blocks, 32/XCD
  int bm = wg >> 3, bn = wg & 7;            // 32 x 8 tiles

  const u16* baseA = A  + (size_t)(bm * 128) * K;
  const u16* baseB = Bt + (size_t)(bn * 256) * K;

  int aLds[2], aG[2];
#pragma unroll
  for (int i = 0; i < 2; ++i){
    int q = (wid * 2 + i) * 1024 + lane * 16;
    int row = q >> 7, c = q & 127;
    int cs = c ^ ((row & 7) << 4);
    aLds[i] = q; aG[i] = row * K + (cs >> 1);
  }
  int bLds[4], bG[4];
#pragma unroll
  for (int j = 0; j < 4; ++j){
    int q = (wid * 4 + j) * 1024 + lane * 16;
    int row = q >> 7, c = q & 127;
    int cs = c ^ ((row & 7) << 4);
    bLds[j] = q; bG[j] = row * K + (cs >> 1);
  }
  auto stage = [&](int t, int buf){
    char* dst = lds + buf * SZ;
#pragma unroll
    for (int i = 0; i < 2; ++i) gload16(baseA + aG[i] + t * 64, (u16*)(dst + aLds[i]));
#pragma unroll
    for (int j = 0; j < 4; ++j) gload16(baseB + bG[j] + t * 64, (u16*)(dst + SZA + bLds[j]));
  };
  auto rdA = [&](const char* Ab, int m, int ks){
    int row = wm * 64 + m * 16 + l16;
    return *(const short8*)(Ab + row * 128 + ((ks * 64 + g4 * 16) ^ ((row & 7) << 4)));
  };
  auto rdB = [&](const char* Bb, int nf, int ks){
    int row = wn * 64 + nf * 16 + l16;
    return *(const short8*)(Bb + row * 128 + ((ks * 64 + g4 * 16) ^ ((row & 7) << 4)));
  };

  f32x4 zero4 = {0.f, 0.f, 0.f, 0.f};
  f32x4 acc[4][4];
#pragma unroll
  for (int i = 0; i < 4; ++i)
#pragma unroll
    for (int j = 0; j < 4; ++j) acc[i][j] = zero4;

  int NK = K >> 6;                  // 32
  stage(0, 0); stage(1, 1);         // 2-tile prologue
  int cur = 0, stb = 2;

  for (int kt = 0; kt < NK; ++kt){
    // entry: own stage(kt) done; stage(kt+1)'s 6 loads may remain in flight
    if (kt + 1 < NK) asm volatile("s_waitcnt vmcnt(6)" ::: "memory");
    else             asm volatile("s_waitcnt vmcnt(0)" ::: "memory");
    __builtin_amdgcn_s_barrier();
    __builtin_amdgcn_sched_barrier(0);

    const char* Ab = lds + cur * SZ;
    const char* Bb = Ab + SZA;

    short8 bf0[4], a0[4], bf1[4], a1[4];
#pragma unroll
    for (int nf = 0; nf < 4; ++nf) bf0[nf] = rdB(Bb, nf, 0);
#pragma unroll
    for (int m = 0; m < 4; ++m)    a0[m]  = rdA(Ab, m, 0);
    if (kt + 2 < NK) stage(kt + 2, stb);            // 2-tile lead
#pragma unroll
    for (int nf = 0; nf < 4; ++nf) bf1[nf] = rdB(Bb, nf, 1);
#pragma unroll
    for (int m = 0; m < 4; ++m)    a1[m]  = rdA(Ab, m, 1);
    __builtin_amdgcn_s_setprio(1);
#pragma unroll
    for (int m = 0; m < 4; ++m)
#pragma unroll
      for (int nf = 0; nf < 4; ++nf)
        acc[m][nf] = __builtin_amdgcn_mfma_f32_16x16x32_bf16(a0[m], bf0[nf], acc[m][nf], 0, 0, 0);
#pragma unroll
    for (int m = 0; m < 4; ++m)
#pragma unroll
      for (int nf = 0; nf < 4; ++nf)
        acc[m][nf] = __builtin_amdgcn_mfma_f32_16x16x32_bf16(a1[m], bf1[nf], acc[m][nf], 0, 0, 0);
    __builtin_amdgcn_s_setprio(0);

    cur = (cur == 2) ? 0 : cur + 1;
    stb = (stb == 2) ? 0 : stb + 1;
  }

#pragma unroll
  for (int mf = 0; mf < 4; ++mf)
#pragma unroll
    for (int nf = 0; nf < 4; ++nf)
#pragma unroll
      for (int r = 0; r < 4; ++r){
        int row = bm * 128 + wm * 64 + mf * 16 + g4 * 4 + r;
        int col = bn * 256 + wn * 64 + nf * 16 + l16;
        C[(size_t)row * N + col] = acc[mf][nf][r];
      }
}

// ---------- V transpose: c1 V-part [bv*256+s][2560+n*64+h] -> vt[(bv*8+n)*64+h][256 s] ----------
__global__ __launch_bounds__(256) void k_vt(const u16* __restrict__ c1, u16* __restrict__ vt){
  __shared__ u16 tile[64][72];
  int bid = blockIdx.x;
  int st = bid & 3, n = (bid >> 2) & 7, bv = bid >> 5;   // bv = b*8+v (0..15)
  int t = threadIdx.x;
  int sr = t >> 2, sc = t & 3;
  const u16* src = c1 + (size_t)(bv * 256 + st * 64 + sr) * 3072 + 2560 + n * 64 + sc * 16;
  short8 a = *(const short8*)src;
  short8 b = *(const short8*)(src + 8);
  *(short8*)&tile[sr][sc * 16]     = a;
  *(short8*)&tile[sr][sc * 16 + 8] = b;
  __syncthreads();
  int h = t >> 2, c2 = t & 3;
  short8 o0, o1;
#pragma unroll
  for (int j = 0; j < 8; ++j) o0[j] = (short)tile[c2 * 16 + j][h];
#pragma unroll
  for (int j = 0; j < 8; ++j) o1[j] = (short)tile[c2 * 16 + 8 + j][h];
  u16* dst = vt + (size_t)((bv * 8 + n) * 64 + h) * 256 + st * 64 + c2 * 16;
  *(short8*)dst       = o0;
  *(short8*)(dst + 8) = o1;
}

// ---------- fused GQA neighbor attention ----------
// block = (b, v, n, qtile32); grid 1024 (4 blocks/CU); 4 waves = 4 GQA groups share K/V.
// swapped QK^T (Q pre-scaled by log2(e)/8 in GEMM epilogue); defer-max (THR=8);
// P packed via v_cvt_pk_bf16_f32; P routed via per-wave LDS to PV A-frag.
__global__ __launch_bounds__(256, 4) void k_attn(const u16* __restrict__ c1,
                                                 const u16* __restrict__ vt,
                                                 u16* __restrict__ att){
  __shared__ u16 Klds[64][72];
  __shared__ u16 Vlds[64][72];
  __shared__ u16 Plds[4][16][72];
  int bid = blockIdx.x;
  int qt = bid & 7, n = (bid >> 3) & 7, v = (bid >> 6) & 7, b = bid >> 9;
  int tid = threadIdx.x;
  int g = tid >> 6, lane = tid & 63, l16 = lane & 15, g4 = lane >> 4;
  int bv = b * 8 + v;
  int rowQ = bv * 256 + qt * 32;
  int qcol = n * 256 + g * 64;

  short8 qf[2][2];
#pragma unroll
  for (int qi = 0; qi < 2; ++qi)
#pragma unroll
    for (int kk = 0; kk < 2; ++kk)
      qf[qi][kk] = *(const short8*)(c1 + (size_t)(rowQ + qi * 16 + l16) * 3072
                                     + qcol + kk * 32 + g4 * 8);

  f32x4 zero4 = {0.f, 0.f, 0.f, 0.f};
  f32x4 O[2][4];
#pragma unroll
  for (int i = 0; i < 2; ++i)
#pragma unroll
    for (int j = 0; j < 4; ++j) O[i][j] = zero4;
  float m2[2]   = {-3.0e38f, -3.0e38f};
  float lsum[2] = {0.f, 0.f};

  int sr = tid >> 2, sc = tid & 3;
  short8 k0, k1, v0, v1;
  {
    int vn = (v + 7) & 7;
    const u16* ks = c1 + (size_t)((b * 8 + vn) * 256 + sr) * 3072 + 2048 + n * 64 + sc * 16;
    k0 = *(const short8*)ks; k1 = *(const short8*)(ks + 8);
    const u16* vs = vt + (size_t)(((b * 8 + vn) * 8 + n) * 64 + sr) * 256 + sc * 16;
    v0 = *(const short8*)vs; v1 = *(const short8*)(vs + 8);
  }

  for (int ti = 0; ti < 8; ++ti){
    __syncthreads();
    *(short8*)&Klds[sr][sc * 16]     = k0;
    *(short8*)&Klds[sr][sc * 16 + 8] = k1;
    *(short8*)&Vlds[sr][sc * 16]     = v0;
    *(short8*)&Vlds[sr][sc * 16 + 8] = v1;
    __syncthreads();
    if (ti < 7){
      int tn = ti + 1;
      int vn = (tn < 4) ? ((v + 7) & 7) : ((v + 1) & 7);
      int tb = (tn & 3) * 64;
      const u16* ks = c1 + (size_t)((b * 8 + vn) * 256 + tb + sr) * 3072 + 2048 + n * 64 + sc * 16;
      k0 = *(const short8*)ks; k1 = *(const short8*)(ks + 8);
      const u16* vs = vt + (size_t)(((b * 8 + vn) * 8 + n) * 64 + sr) * 256 + tb + sc * 16;
      v0 = *(const short8*)vs; v1 = *(const short8*)(vs + 8);
    }
    short8 kf[4][2], vf[2][4];
#pragma unroll
    for (int kt = 0; kt < 4; ++kt)
#pragma unroll
      for (int ks = 0; ks < 2; ++ks)
        kf[kt][ks] = *(const short8*)&Klds[kt * 16 + l16][ks * 32 + g4 * 8];
#pragma unroll
    for (int ks = 0; ks < 2; ++ks)
#pragma unroll
      for (int hi = 0; hi < 4; ++hi)
        vf[ks][hi] = *(const short8*)&Vlds[hi * 16 + l16][ks * 32 + g4 * 8];

#pragma unroll
    for (int qi = 0; qi < 2; ++qi){
      f32x4 sa[4];
#pragma unroll
      for (int kt = 0; kt < 4; ++kt){
        sa[kt] = zero4;
#pragma unroll
        for (int ks = 0; ks < 2; ++ks)
          sa[kt] = __builtin_amdgcn_mfma_f32_16x16x32_bf16(kf[kt][ks], qf[qi][ks], sa[kt], 0, 0, 0);
      }
      // scores already in exp2 domain (Q pre-scaled). Row max over 16 local + cross-group.
      float pmax = sa[0][0];
#pragma unroll
      for (int kt = 0; kt < 4; ++kt)
#pragma unroll
        for (int r = 0; r < 4; ++r) pmax = fmaxf(pmax, sa[kt][r]);
      pmax = fmaxf(pmax, __shfl_xor(pmax, 16));
      pmax = fmaxf(pmax, __shfl_xor(pmax, 32));
      // defer-max: rescale only when the running max grew by > 8 (P bounded by 2^8)
      if (__any(pmax > m2[qi] + 8.f)){
        float mnew  = fmaxf(m2[qi], pmax);
        float alpha = exp2f(m2[qi] - mnew);
        m2[qi] = mnew;
        lsum[qi] *= alpha;
        float ab[4];
#pragma unroll
        for (int r = 0; r < 4; ++r) ab[r] = __shfl(alpha, g4 * 4 + r);
#pragma unroll
        for (int hi = 0; hi < 4; ++hi)
#pragma unroll
          for (int r = 0; r < 4; ++r) O[qi][hi][r] *= ab[r];
      }
      float m = m2[qi];
      float psum = 0.f;
      u32 w[4][2];
#pragma unroll
      for (int kt = 0; kt < 4; ++kt){
        float p0 = exp2f(sa[kt][0] - m);
        float p1 = exp2f(sa[kt][1] - m);
        float p2 = exp2f(sa[kt][2] - m);
        float p3 = exp2f(sa[kt][3] - m);
        psum += (p0 + p1) + (p2 + p3);
        w[kt][0] = cvtpk(p0, p1);
        w[kt][1] = cvtpk(p2, p3);
      }
      psum += __shfl_xor(psum, 16);
      psum += __shfl_xor(psum, 32);
      lsum[qi] += psum;
      // P -> per-wave LDS (key = kt*16 + g4*4 + {0..3}, qrow = l16)
      u32* prow = (u32*)&Plds[g][l16][0];
#pragma unroll
      for (int kt = 0; kt < 4; ++kt){
        prow[kt * 8 + g4 * 2]     = w[kt][0];
        prow[kt * 8 + g4 * 2 + 1] = w[kt][1];
      }
      short8 pa[2];
#pragma unroll
      for (int ks = 0; ks < 2; ++ks)
        pa[ks] = *(const short8*)&Plds[g][l16][ks * 32 + g4 * 8];
#pragma unroll
      for (int hi = 0; hi < 4; ++hi)
#pragma unroll
        for (int ks = 0; ks < 2; ++ks)
          O[qi][hi] = __builtin_amdgcn_mfma_f32_16x16x32_bf16(pa[ks], vf[ks][hi], O[qi][hi], 0, 0, 0);
    }
  }
#pragma unroll
  for (int qi = 0; qi < 2; ++qi){
    float lb[4];
#pragma unroll
    for (int r = 0; r < 4; ++r) lb[r] = 1.0f / __shfl(lsum[qi], g4 * 4 + r);
#pragma unroll
    for (int hi = 0; hi < 4; ++hi)
#pragma unroll
      for (int r = 0; r < 4; ++r){
        int row = rowQ + qi * 16 + g4 * 4 + r;
        int col = qcol + hi * 16 + l16;
        att[(size_t)row * 2048 + col] = f2bf(O[qi][hi][r] * lb[r]);
      }
  }
}

extern "C" void kernel_launch(void* const* d_in, const int* in_sizes, int n_in,
                              void* d_out, int out_size, void* d_ws, size_t ws_size,
                              hipStream_t stream){
  const float* x   = (const float*)d_in[0];
  const float* wq  = (const float*)d_in[1];
  const float* wkv = (const float*)d_in[2];
  const float* wo  = (const float*)d_in[3];
  float* out = (float*)d_out;
  char* ws = (char*)d_ws;

  // workspace layout (67,108,864 B total)
  u16* x_bf  = (u16*)(ws);               // [4096][2048] bf16, 16.78 MB (aliased by att)
  u16* wqkvt = (u16*)(ws + 16777216);    // [3072][2048] bf16, 12.58 MB
  u16* wot   = (u16*)(ws + 29360128);    // [2048][2048] bf16,  8.39 MB
  u16* c1    = (u16*)(ws + 37748736);    // [4096][3072] bf16, 25.17 MB (Q|K|V)
  u16* vt    = (u16*)(ws + 62914560);    // [16*8][64][256] bf16, 4.19 MB
  u16* att   = x_bf;                     // alias: x_bf dead after GEMM1

  k_cvt_bf16<<<4096, 256, 0, stream>>>(x, x_bf, 1048576);
  k_transpose_w<<<4096, 256, 0, stream>>>(wq,  wqkvt,               2048, 2048);
  k_transpose_w<<<2048, 256, 0, stream>>>(wkv, wqkvt + 2048 * 2048, 2048, 1024);
  k_transpose_w<<<4096, 256, 0, stream>>>(wo,  wot,                 2048, 2048);
  // QKV projection (Q cols pre-scaled by log2(e)/8): 256x192 tiles, 256 blocks
  k_gemm8p<192, 3, 3, true, u16><<<256, 512, 0, stream>>>(x_bf, wqkvt, c1, 3072, 2048);
  k_vt<<<512, 256, 0, stream>>>(c1, vt);
  k_attn<<<1024, 256, 0, stream>>>(c1, vt, att);
  // output projection: 128x256 tiles, 256 blocks, 3-buffer counted-vmcnt pipeline
  k_gemm_o<<<256, 512, 0, stream>>>(att, wot, out, 2048, 2048);
}

// Round 7
// 149.210 us; speedup vs baseline: 1.4134x; 1.4134x over previous
//
#include <hip/hip_runtime.h>
#include <stdint.h>

typedef unsigned short u16;
typedef unsigned int   u32;
typedef short short8 __attribute__((ext_vector_type(8)));
typedef float f32x4  __attribute__((ext_vector_type(4)));

// ---------- helpers ----------
__device__ __forceinline__ u16 f2bf(float f){
  u32 u = __builtin_bit_cast(u32, f);
  u32 r = (u + 0x7FFFu + ((u >> 16) & 1u)) >> 16;   // RNE
  return (u16)r;
}
__device__ __forceinline__ u32 cvtpk(float a, float b){   // lo=bf16(a), hi=bf16(b), RNE
  u32 r; asm("v_cvt_pk_bf16_f32 %0, %1, %2" : "=v"(r) : "v"(a), "v"(b)); return r;
}
// async global->LDS, 16B per lane. LDS dest = wave-uniform base + lane*16.
__device__ __forceinline__ void gload16(const u16* g, u16* l){
  __builtin_amdgcn_global_load_lds((const __attribute__((address_space(1))) void*)g,
                                   (__attribute__((address_space(3))) void*)l, 16, 0, 0);
}

// ---------- x f32 -> bf16 ----------
__global__ __launch_bounds__(256) void k_cvt_bf16(const float* __restrict__ x,
                                                  u16* __restrict__ y, int n8){
  int i = blockIdx.x * 256 + threadIdx.x;
  if (i >= n8) return;
  const float4* p = (const float4*)x + (size_t)i * 2;
  float4 a = p[0], b = p[1];
  short8 o;
  o[0] = f2bf(a.x); o[1] = f2bf(a.y); o[2] = f2bf(a.z); o[3] = f2bf(a.w);
  o[4] = f2bf(b.x); o[5] = f2bf(b.y); o[6] = f2bf(b.z); o[7] = f2bf(b.w);
  *(short8*)(y + (size_t)i * 8) = o;
}

// ---------- weight transpose: in f32[R][C] -> out bf16[C][R] ----------
__global__ __launch_bounds__(256) void k_transpose_w(const float* __restrict__ in,
                                                     u16* __restrict__ out, int R, int C){
  __shared__ float tile[32][33];
  int nc = C >> 5;
  int cb = blockIdx.x % nc, rb = blockIdx.x / nc;
  int tx = threadIdx.x & 31, ty = threadIdx.x >> 5;
#pragma unroll
  for (int i = 0; i < 4; ++i){
    int r = rb * 32 + ty + i * 8;
    tile[ty + i * 8][tx] = in[(size_t)r * C + cb * 32 + tx];
  }
  __syncthreads();
#pragma unroll
  for (int i = 0; i < 4; ++i){
    int c = cb * 32 + ty + i * 8;
    out[(size_t)c * R + rb * 32 + tx] = f2bf(tile[tx][ty + i * 8]);
  }
}

// ---------- QKV GEMM: c1[4096][3072] = A[4096][2048] * Bt[3072][2048]^T ----------
// BM=256, BN=192, BK=64, 8 waves (2m x 4n), 2 LDS buffers, 4 phases/K-tile,
// reads one phase ahead, XOR-swizzled LDS, setprio, Q-columns pre-scaled by log2(e)/8.
template<int BN, int NFRAG, int BLOADS, bool QSCALE, typename CT>
__global__ __launch_bounds__(512, 2) void k_gemm8p(const u16* __restrict__ A,
                                                   const u16* __restrict__ Bt,
                                                   CT* __restrict__ C,
                                                   int N, int K){
  constexpr int SZA = 256 * 128;
  constexpr int SZB = BN * 128;
  constexpr int SZ  = SZA + SZB;
  constexpr int WT_N = BN / 4;
  __shared__ char lds[2 * SZ];

  int tid = threadIdx.x, lane = tid & 63, wid = tid >> 6;
  int l16 = lane & 15, g4 = lane >> 4;
  int wm = wid >> 2, wn = wid & 3;
  int bid = blockIdx.x;
  int wg = (bid & 7) * 32 + (bid >> 3);
  int bm = wg >> 4, bn = wg & 15;

  const u16* baseA = A  + (size_t)(bm * 256) * K;
  const u16* baseB = Bt + (size_t)(bn * BN) * K;

  int aLds[4], aG[4];
#pragma unroll
  for (int i = 0; i < 4; ++i){
    int q = (wid * 4 + i) * 1024 + lane * 16;
    int row = q >> 7, c = q & 127;
    int cs = c ^ ((row & 7) << 4);
    aLds[i] = q; aG[i] = row * K + (cs >> 1);
  }
  int bLds[BLOADS], bG[BLOADS];
#pragma unroll
  for (int j = 0; j < BLOADS; ++j){
    int q = (wid * BLOADS + j) * 1024 + lane * 16;
    int row = q >> 7, c = q & 127;
    int cs = c ^ ((row & 7) << 4);
    bLds[j] = q; bG[j] = row * K + (cs >> 1);
  }
  auto stageA = [&](int t){
    char* dst = lds + (t & 1) * SZ;
#pragma unroll
    for (int i = 0; i < 4; ++i) gload16(baseA + aG[i] + t * 64, (u16*)(dst + aLds[i]));
  };
  auto stageB = [&](int t){
    char* dst = lds + (t & 1) * SZ + SZA;
#pragma unroll
    for (int j = 0; j < BLOADS; ++j) gload16(baseB + bG[j] + t * 64, (u16*)(dst + bLds[j]));
  };
  auto rdA = [&](const char* Ab, int m, int ks){
    int row = wm * 128 + m * 16 + l16;
    return *(const short8*)(Ab + row * 128 + ((ks * 64 + g4 * 16) ^ ((row & 7) << 4)));
  };
  auto rdB = [&](const char* Bb, int nf, int ks){
    int row = wn * WT_N + nf * 16 + l16;
    return *(const short8*)(Bb + row * 128 + ((ks * 64 + g4 * 16) ^ ((row & 7) << 4)));
  };

  f32x4 zero4 = {0.f, 0.f, 0.f, 0.f};
  f32x4 acc[8][NFRAG];
#pragma unroll
  for (int i = 0; i < 8; ++i)
#pragma unroll
    for (int j = 0; j < NFRAG; ++j) acc[i][j] = zero4;

  int NK = K >> 6;
  stageA(0); stageB(0);
  asm volatile("s_waitcnt vmcnt(0)" ::: "memory");

  for (int kt = 0; kt < NK; ++kt){
    const char* Ab = lds + (kt & 1) * SZ;
    const char* Bb = Ab + SZA;
    bool st = (kt + 1 < NK);
    __builtin_amdgcn_s_barrier();
    // phase a
    short8 bf0[NFRAG], a0[4], a1[4], bf1[NFRAG], a2[4], a3[4];
#pragma unroll
    for (int nf = 0; nf < NFRAG; ++nf) bf0[nf] = rdB(Bb, nf, 0);
#pragma unroll
    for (int m = 0; m < 4; ++m) a0[m] = rdA(Ab, m, 0);
    if (st) stageA(kt + 1);
#pragma unroll
    for (int m = 0; m < 4; ++m) a1[m] = rdA(Ab, 4 + m, 0);
    __builtin_amdgcn_s_setprio(1);
#pragma unroll
    for (int m = 0; m < 4; ++m)
#pragma unroll
      for (int nf = 0; nf < NFRAG; ++nf)
        acc[m][nf] = __builtin_amdgcn_mfma_f32_16x16x32_bf16(a0[m], bf0[nf], acc[m][nf], 0, 0, 0);
    __builtin_amdgcn_s_setprio(0);
    __builtin_amdgcn_s_barrier();
    // phase b
    if (st) stageB(kt + 1);
#pragma unroll
    for (int nf = 0; nf < NFRAG; ++nf) bf1[nf] = rdB(Bb, nf, 1);
#pragma unroll
    for (int m = 0; m < 4; ++m) a2[m] = rdA(Ab, m, 1);
    __builtin_amdgcn_s_setprio(1);
#pragma unroll
    for (int m = 0; m < 4; ++m)
#pragma unroll
      for (int nf = 0; nf < NFRAG; ++nf)
        acc[4 + m][nf] = __builtin_amdgcn_mfma_f32_16x16x32_bf16(a1[m], bf0[nf], acc[4 + m][nf], 0, 0, 0);
    __builtin_amdgcn_s_setprio(0);
    __builtin_amdgcn_s_barrier();
    // phase c
#pragma unroll
    for (int m = 0; m < 4; ++m) a3[m] = rdA(Ab, 4 + m, 1);
    __builtin_amdgcn_s_setprio(1);
#pragma unroll
    for (int m = 0; m < 4; ++m)
#pragma unroll
      for (int nf = 0; nf < NFRAG; ++nf)
        acc[m][nf] = __builtin_amdgcn_mfma_f32_16x16x32_bf16(a2[m], bf1[nf], acc[m][nf], 0, 0, 0);
    __builtin_amdgcn_s_setprio(0);
    __builtin_amdgcn_s_barrier();
    // phase d
    __builtin_amdgcn_s_setprio(1);
#pragma unroll
    for (int m = 0; m < 4; ++m)
#pragma unroll
      for (int nf = 0; nf < NFRAG; ++nf)
        acc[4 + m][nf] = __builtin_amdgcn_mfma_f32_16x16x32_bf16(a3[m], bf1[nf], acc[4 + m][nf], 0, 0, 0);
    __builtin_amdgcn_s_setprio(0);
    if (st) asm volatile("s_waitcnt vmcnt(0)" ::: "memory");
  }

#pragma unroll
  for (int mf = 0; mf < 8; ++mf)
#pragma unroll
    for (int nf = 0; nf < NFRAG; ++nf)
#pragma unroll
      for (int r = 0; r < 4; ++r){
        int row = bm * 256 + wm * 128 + mf * 16 + g4 * 4 + r;
        int col = bn * BN + wn * WT_N + nf * 16 + l16;
        float vv = acc[mf][nf][r];
        if constexpr (QSCALE) { if (col < 2048) vv *= 0.18033688011112042f; }  // log2(e)/8
        if constexpr (sizeof(CT) == 2) C[(size_t)row * N + col] = (CT)f2bf(vv);
        else                           C[(size_t)row * N + col] = (CT)vv;
      }
}

// ---------- O-proj GEMM: out[4096][2048] = att[4096][2048] * wot[2048][2048]^T ----------
// BM=128, BN=256, BK=64, 8 waves (2m x 4n) wave-tile 64x64, 3 LDS buffers (144KB),
// 2-K-tile prefetch lead, counted vmcnt(6), ONE barrier per K-tile (T3+T4).
__global__ __launch_bounds__(512, 1) void k_gemm_o(const u16* __restrict__ A,
                                                   const u16* __restrict__ Bt,
                                                   float* __restrict__ C,
                                                   int N, int K){
  constexpr int SZA = 128 * 128;   // 16 KB
  constexpr int SZB = 256 * 128;   // 32 KB
  constexpr int SZ  = SZA + SZB;   // 48 KB
  __shared__ char lds[3 * SZ];     // 144 KB

  int tid = threadIdx.x, lane = tid & 63, wid = tid >> 6;
  int l16 = lane & 15, g4 = lane >> 4;
  int wm = wid >> 2, wn = wid & 3;
  int bid = blockIdx.x;
  int wg = (bid & 7) * 32 + (bid >> 3);     // 256 blocks, 32/XCD
  int bm = wg >> 3, bn = wg & 7;            // 32 x 8 tiles

  const u16* baseA = A  + (size_t)(bm * 128) * K;
  const u16* baseB = Bt + (size_t)(bn * 256) * K;

  int aLds[2], aG[2];
#pragma unroll
  for (int i = 0; i < 2; ++i){
    int q = (wid * 2 + i) * 1024 + lane * 16;
    int row = q >> 7, c = q & 127;
    int cs = c ^ ((row & 7) << 4);
    aLds[i] = q; aG[i] = row * K + (cs >> 1);
  }
  int bLds[4], bG[4];
#pragma unroll
  for (int j = 0; j < 4; ++j){
    int q = (wid * 4 + j) * 1024 + lane * 16;
    int row = q >> 7, c = q & 127;
    int cs = c ^ ((row & 7) << 4);
    bLds[j] = q; bG[j] = row * K + (cs >> 1);
  }
  auto stage = [&](int t, int buf){
    char* dst = lds + buf * SZ;
#pragma unroll
    for (int i = 0; i < 2; ++i) gload16(baseA + aG[i] + t * 64, (u16*)(dst + aLds[i]));
#pragma unroll
    for (int j = 0; j < 4; ++j) gload16(baseB + bG[j] + t * 64, (u16*)(dst + SZA + bLds[j]));
  };
  auto rdA = [&](const char* Ab, int m, int ks){
    int row = wm * 64 + m * 16 + l16;
    return *(const short8*)(Ab + row * 128 + ((ks * 64 + g4 * 16) ^ ((row & 7) << 4)));
  };
  auto rdB = [&](const char* Bb, int nf, int ks){
    int row = wn * 64 + nf * 16 + l16;
    return *(const short8*)(Bb + row * 128 + ((ks * 64 + g4 * 16) ^ ((row & 7) << 4)));
  };

  f32x4 zero4 = {0.f, 0.f, 0.f, 0.f};
  f32x4 acc[4][4];
#pragma unroll
  for (int i = 0; i < 4; ++i)
#pragma unroll
    for (int j = 0; j < 4; ++j) acc[i][j] = zero4;

  int NK = K >> 6;                  // 32
  stage(0, 0); stage(1, 1);         // 2-tile prologue
  int cur = 0, stb = 2;

  for (int kt = 0; kt < NK; ++kt){
    // entry: own stage(kt) done; stage(kt+1)'s 6 loads may remain in flight
    if (kt + 1 < NK) asm volatile("s_waitcnt vmcnt(6)" ::: "memory");
    else             asm volatile("s_waitcnt vmcnt(0)" ::: "memory");
    __builtin_amdgcn_s_barrier();
    __builtin_amdgcn_sched_barrier(0);

    const char* Ab = lds + cur * SZ;
    const char* Bb = Ab + SZA;

    short8 bf0[4], a0[4], bf1[4], a1[4];
#pragma unroll
    for (int nf = 0; nf < 4; ++nf) bf0[nf] = rdB(Bb, nf, 0);
#pragma unroll
    for (int m = 0; m < 4; ++m)    a0[m]  = rdA(Ab, m, 0);
    if (kt + 2 < NK) stage(kt + 2, stb);            // 2-tile lead
#pragma unroll
    for (int nf = 0; nf < 4; ++nf) bf1[nf] = rdB(Bb, nf, 1);
#pragma unroll
    for (int m = 0; m < 4; ++m)    a1[m]  = rdA(Ab, m, 1);
    __builtin_amdgcn_s_setprio(1);
#pragma unroll
    for (int m = 0; m < 4; ++m)
#pragma unroll
      for (int nf = 0; nf < 4; ++nf)
        acc[m][nf] = __builtin_amdgcn_mfma_f32_16x16x32_bf16(a0[m], bf0[nf], acc[m][nf], 0, 0, 0);
#pragma unroll
    for (int m = 0; m < 4; ++m)
#pragma unroll
      for (int nf = 0; nf < 4; ++nf)
        acc[m][nf] = __builtin_amdgcn_mfma_f32_16x16x32_bf16(a1[m], bf1[nf], acc[m][nf], 0, 0, 0);
    __builtin_amdgcn_s_setprio(0);

    cur = (cur == 2) ? 0 : cur + 1;
    stb = (stb == 2) ? 0 : stb + 1;
  }

#pragma unroll
  for (int mf = 0; mf < 4; ++mf)
#pragma unroll
    for (int nf = 0; nf < 4; ++nf)
#pragma unroll
      for (int r = 0; r < 4; ++r){
        int row = bm * 128 + wm * 64 + mf * 16 + g4 * 4 + r;
        int col = bn * 256 + wn * 64 + nf * 16 + l16;
        C[(size_t)row * N + col] = acc[mf][nf][r];
      }
}

// ---------- V transpose: c1 V-part [bv*256+s][2560+n*64+h] -> vt[(bv*8+n)*64+h][256 s] ----------
__global__ __launch_bounds__(256) void k_vt(const u16* __restrict__ c1, u16* __restrict__ vt){
  __shared__ u16 tile[64][72];
  int bid = blockIdx.x;
  int st = bid & 3, n = (bid >> 2) & 7, bv = bid >> 5;   // bv = b*8+v (0..15)
  int t = threadIdx.x;
  int sr = t >> 2, sc = t & 3;
  const u16* src = c1 + (size_t)(bv * 256 + st * 64 + sr) * 3072 + 2560 + n * 64 + sc * 16;
  short8 a = *(const short8*)src;
  short8 b = *(const short8*)(src + 8);
  *(short8*)&tile[sr][sc * 16]     = a;
  *(short8*)&tile[sr][sc * 16 + 8] = b;
  __syncthreads();
  int h = t >> 2, c2 = t & 3;
  short8 o0, o1;
#pragma unroll
  for (int j = 0; j < 8; ++j) o0[j] = (short)tile[c2 * 16 + j][h];
#pragma unroll
  for (int j = 0; j < 8; ++j) o1[j] = (short)tile[c2 * 16 + 8 + j][h];
  u16* dst = vt + (size_t)((bv * 8 + n) * 64 + h) * 256 + st * 64 + c2 * 16;
  *(short8*)dst       = o0;
  *(short8*)(dst + 8) = o1;
}

// ---------- fused GQA neighbor attention ----------
// block = (b, v, n, qtile64); grid 512; 4 waves = 4 GQA groups sharing K/V LDS.
// Round-5 geometry (QBLK=64, VGPR cap 256 -> no spill) + round-6 micro-opts:
// Q pre-scaled by log2(e)/8 in GEMM epilogue; defer-max (THR=8); cvt_pk packing.
__global__ __launch_bounds__(256, 2) void k_attn(const u16* __restrict__ c1,
                                                 const u16* __restrict__ vt,
                                                 u16* __restrict__ att){
  __shared__ u16 Klds[64][72];
  __shared__ u16 Vlds[64][72];
  __shared__ u16 Plds[4][16][72];
  int bid = blockIdx.x;
  int qt = bid & 3, n = (bid >> 2) & 7, v = (bid >> 5) & 7, b = bid >> 8;
  int tid = threadIdx.x;
  int g = tid >> 6, lane = tid & 63, l16 = lane & 15, g4 = lane >> 4;
  int bv = b * 8 + v;
  int rowQ = bv * 256 + qt * 64;
  int qcol = n * 256 + g * 64;

  short8 qf[4][2];
#pragma unroll
  for (int qi = 0; qi < 4; ++qi)
#pragma unroll
    for (int kk = 0; kk < 2; ++kk)
      qf[qi][kk] = *(const short8*)(c1 + (size_t)(rowQ + qi * 16 + l16) * 3072
                                     + qcol + kk * 32 + g4 * 8);

  f32x4 zero4 = {0.f, 0.f, 0.f, 0.f};
  f32x4 O[4][4];
#pragma unroll
  for (int i = 0; i < 4; ++i)
#pragma unroll
    for (int j = 0; j < 4; ++j) O[i][j] = zero4;
  float m2[4]   = {-3.0e38f, -3.0e38f, -3.0e38f, -3.0e38f};
  float lsum[4] = {0.f, 0.f, 0.f, 0.f};

  int sr = tid >> 2, sc = tid & 3;
  short8 k0, k1, v0, v1;
  {
    int vn = (v + 7) & 7;
    const u16* ks = c1 + (size_t)((b * 8 + vn) * 256 + sr) * 3072 + 2048 + n * 64 + sc * 16;
    k0 = *(const short8*)ks; k1 = *(const short8*)(ks + 8);
    const u16* vs = vt + (size_t)(((b * 8 + vn) * 8 + n) * 64 + sr) * 256 + sc * 16;
    v0 = *(const short8*)vs; v1 = *(const short8*)(vs + 8);
  }

  for (int ti = 0; ti < 8; ++ti){
    __syncthreads();
    *(short8*)&Klds[sr][sc * 16]     = k0;
    *(short8*)&Klds[sr][sc * 16 + 8] = k1;
    *(short8*)&Vlds[sr][sc * 16]     = v0;
    *(short8*)&Vlds[sr][sc * 16 + 8] = v1;
    __syncthreads();
    if (ti < 7){
      int tn = ti + 1;
      int vn = (tn < 4) ? ((v + 7) & 7) : ((v + 1) & 7);
      int tb = (tn & 3) * 64;
      const u16* ks = c1 + (size_t)((b * 8 + vn) * 256 + tb + sr) * 3072 + 2048 + n * 64 + sc * 16;
      k0 = *(const short8*)ks; k1 = *(const short8*)(ks + 8);
      const u16* vs = vt + (size_t)(((b * 8 + vn) * 8 + n) * 64 + sr) * 256 + tb + sc * 16;
      v0 = *(const short8*)vs; v1 = *(const short8*)(vs + 8);
    }
    short8 kf[4][2], vf[2][4];
#pragma unroll
    for (int kt = 0; kt < 4; ++kt)
#pragma unroll
      for (int ks = 0; ks < 2; ++ks)
        kf[kt][ks] = *(const short8*)&Klds[kt * 16 + l16][ks * 32 + g4 * 8];
#pragma unroll
    for (int ks = 0; ks < 2; ++ks)
#pragma unroll
      for (int hi = 0; hi < 4; ++hi)
        vf[ks][hi] = *(const short8*)&Vlds[hi * 16 + l16][ks * 32 + g4 * 8];

#pragma unroll
    for (int qi = 0; qi < 4; ++qi){
      f32x4 sa[4];
#pragma unroll
      for (int kt = 0; kt < 4; ++kt){
        sa[kt] = zero4;
#pragma unroll
        for (int ks = 0; ks < 2; ++ks)
          sa[kt] = __builtin_amdgcn_mfma_f32_16x16x32_bf16(kf[kt][ks], qf[qi][ks], sa[kt], 0, 0, 0);
      }
      // scores already in exp2 domain (Q pre-scaled). Row max (qrow = l16).
      float pmax = sa[0][0];
#pragma unroll
      for (int kt = 0; kt < 4; ++kt)
#pragma unroll
        for (int r = 0; r < 4; ++r) pmax = fmaxf(pmax, sa[kt][r]);
      pmax = fmaxf(pmax, __shfl_xor(pmax, 16));
      pmax = fmaxf(pmax, __shfl_xor(pmax, 32));
      // defer-max: rescale only when running max grew by > 8 (P bounded by 2^8)
      if (__any(pmax > m2[qi] + 8.f)){
        float mnew  = fmaxf(m2[qi], pmax);
        float alpha = exp2f(m2[qi] - mnew);
        m2[qi] = mnew;
        lsum[qi] *= alpha;
        float ab[4];
#pragma unroll
        for (int r = 0; r < 4; ++r) ab[r] = __shfl(alpha, g4 * 4 + r);
#pragma unroll
        for (int hi = 0; hi < 4; ++hi)
#pragma unroll
          for (int r = 0; r < 4; ++r) O[qi][hi][r] *= ab[r];
      }
      float m = m2[qi];
      float psum = 0.f;
      u32 w[4][2];
#pragma unroll
      for (int kt = 0; kt < 4; ++kt){
        float p0 = exp2f(sa[kt][0] - m);
        float p1 = exp2f(sa[kt][1] - m);
        float p2 = exp2f(sa[kt][2] - m);
        float p3 = exp2f(sa[kt][3] - m);
        psum += (p0 + p1) + (p2 + p3);
        w[kt][0] = cvtpk(p0, p1);
        w[kt][1] = cvtpk(p2, p3);
      }
      psum += __shfl_xor(psum, 16);
      psum += __shfl_xor(psum, 32);
      lsum[qi] += psum;
      // P -> per-wave LDS (key = kt*16 + g4*4 + {0..3}, qrow = l16)
      u32* prow = (u32*)&Plds[g][l16][0];
#pragma unroll
      for (int kt = 0; kt < 4; ++kt){
        prow[kt * 8 + g4 * 2]     = w[kt][0];
        prow[kt * 8 + g4 * 2 + 1] = w[kt][1];
      }
      short8 pa[2];
#pragma unroll
      for (int ks = 0; ks < 2; ++ks)
        pa[ks] = *(const short8*)&Plds[g][l16][ks * 32 + g4 * 8];
#pragma unroll
      for (int hi = 0; hi < 4; ++hi)
#pragma unroll
        for (int ks = 0; ks < 2; ++ks)
          O[qi][hi] = __builtin_amdgcn_mfma_f32_16x16x32_bf16(pa[ks], vf[ks][hi], O[qi][hi], 0, 0, 0);
    }
  }
#pragma unroll
  for (int qi = 0; qi < 4; ++qi){
    float lb[4];
#pragma unroll
    for (int r = 0; r < 4; ++r) lb[r] = 1.0f / __shfl(lsum[qi], g4 * 4 + r);
#pragma unroll
    for (int hi = 0; hi < 4; ++hi)
#pragma unroll
      for (int r = 0; r < 4; ++r){
        int row = rowQ + qi * 16 + g4 * 4 + r;
        int col = qcol + hi * 16 + l16;
        att[(size_t)row * 2048 + col] = f2bf(O[qi][hi][r] * lb[r]);
      }
  }
}

extern "C" void kernel_launch(void* const* d_in, const int* in_sizes, int n_in,
                              void* d_out, int out_size, void* d_ws, size_t ws_size,
                              hipStream_t stream){
  const float* x   = (const float*)d_in[0];
  const float* wq  = (const float*)d_in[1];
  const float* wkv = (const float*)d_in[2];
  const float* wo  = (const float*)d_in[3];
  float* out = (float*)d_out;
  char* ws = (char*)d_ws;

  // workspace layout (67,108,864 B total)
  u16* x_bf  = (u16*)(ws);               // [4096][2048] bf16, 16.78 MB (aliased by att)
  u16* wqkvt = (u16*)(ws + 16777216);    // [3072][2048] bf16, 12.58 MB
  u16* wot   = (u16*)(ws + 29360128);    // [2048][2048] bf16,  8.39 MB
  u16* c1    = (u16*)(ws + 37748736);    // [4096][3072] bf16, 25.17 MB (Q|K|V)
  u16* vt    = (u16*)(ws + 62914560);    // [16*8][64][256] bf16, 4.19 MB
  u16* att   = x_bf;                     // alias: x_bf dead after GEMM1

  k_cvt_bf16<<<4096, 256, 0, stream>>>(x, x_bf, 1048576);
  k_transpose_w<<<4096, 256, 0, stream>>>(wq,  wqkvt,               2048, 2048);
  k_transpose_w<<<2048, 256, 0, stream>>>(wkv, wqkvt + 2048 * 2048, 2048, 1024);
  k_transpose_w<<<4096, 256, 0, stream>>>(wo,  wot,                 2048, 2048);
  // QKV projection (Q cols pre-scaled by log2(e)/8): 256x192 tiles, 256 blocks
  k_gemm8p<192, 3, 3, true, u16><<<256, 512, 0, stream>>>(x_bf, wqkvt, c1, 3072, 2048);
  k_vt<<<512, 256, 0, stream>>>(c1, vt);
  k_attn<<<512, 256, 0, stream>>>(c1, vt, att);
  // output projection: 128x256 tiles, 256 blocks, 3-buffer counted-vmcnt pipeline
  k_gemm_o<<<256, 512, 0, stream>>>(att, wot, out, 2048, 2048);
}